// Round 10
// baseline (182.824 us; speedup 1.0000x reference)
//
#include <hip/hip_runtime.h>

#define LSEQ 8194
#define NPOS 2048

typedef _Float16 f16x8 __attribute__((ext_vector_type(8)));
typedef _Float16 f16x2 __attribute__((ext_vector_type(2)));
typedef __attribute__((ext_vector_type(4))) float f32x4;

static __device__ __forceinline__ float tanh_fast(float x){
    float p = __expf(2.0f * x);
    float r = __builtin_amdgcn_rcpf(1.0f + p);
    return 1.0f - 2.0f * r;
}
// sum 3 packed-f16x2 taps + relu (v_pk_add_f16 + v_pk_max_f16)
static __device__ __forceinline__ unsigned h3relu(unsigned a, unsigned b, unsigned c){
    union { f16x2 h; unsigned u; } x, y, z, r;
    x.u = a; y.u = b; z.u = c;
    f16x2 s = x.h + y.h + z.h;
    f16x2 zero = { (_Float16)0.0f, (_Float16)0.0f };
    r.h = __builtin_elementwise_max(s, zero);
    return r.u;
}
static __device__ __forceinline__ unsigned hpack(float a, float b){
    union { f16x2 h; unsigned u; } pk;
    pk.h = (f16x2){ (_Float16)a, (_Float16)b };
    return pk.u;
}

// K0: precompute shared tables once:
//  tblp: perm-layout tap table [3][26][20] u32 (f16x2), pos p=(cp&3)*4+(cp>>2)
//  tblg: g-layout  tap table [3][26][17] u32 (f16x2)
//  wah : Wa as f16 row-major 128x128 (8192 u32 pairs)
__global__ __launch_bounds__(256) void k_tbl(
        const float* __restrict__ emb, const float* __restrict__ cw,
        const float* __restrict__ cb, const float* __restrict__ Wa,
        unsigned* __restrict__ tblp, unsigned* __restrict__ tblg,
        unsigned* __restrict__ wah)
{
    int gid = blockIdx.x*256 + threadIdx.x;
    if (gid < 1248){
        int k = gid / 416;          // 416 = 26*16
        int rem = gid - k*416;
        int l = rem >> 4;
        int cp = rem & 15;
        int c0 = cp*2;
        float v0 = 0.f, v1 = 0.f;
        #pragma unroll
        for (int i = 0; i < 5; i++){
            float e = emb[l*5 + i];
            v0 += cw[(c0*5 + i)*3 + k] * e;
            v1 += cw[((c0+1)*5 + i)*3 + k] * e;
        }
        if (k == 2){ v0 += cb[c0]; v1 += cb[c0+1]; }
        unsigned u = hpack(v0, v1);
        tblp[k*520 + l*20 + (cp & 3)*4 + (cp >> 2)] = u;
        tblg[k*442 + l*17 + cp] = u;
    }
    for (int i = gid; i < 8192; i += 1280)
        wah[i] = hpack(Wa[2*i], Wa[2*i + 1]);
}

// KA: fused conv + attention-GEMM -> e[b,n]. 128 n per block, 2 sub-tiles.
// Wave w owns d-dims [32w,32w+32). Letters staged as pre-scaled byte offsets
// (l*80, ushort). 6 resident blocks/CU target; own-rg B-frags kept in regs.
__global__ __launch_bounds__(256, 6) void ka_conv_gemm(
        const int* __restrict__ seq, const unsigned* __restrict__ tblp,
        const unsigned* __restrict__ wah, const float* __restrict__ va,
        float* __restrict__ ws_e)
{
    __shared__ __align__(16) unsigned tblH[1560];      // 6240 B
    __shared__ unsigned short seqw16[4][132];          // pre-scaled offsets (x80)
    __shared__ uint4 bshare[16*64];                    // 16 KB f16 B-frags
    __shared__ float epar[4][64];

    int tid = threadIdx.x;
    int b   = blockIdx.y;
    int n0  = blockIdx.x * 128;

    for (int i = tid; i < 390; i += 256)
        ((uint4*)tblH)[i] = ((const uint4*)tblp)[i];
    const int* sb = seq + (size_t)b * LSEQ;
    for (int i = tid; i < 4*130; i += 256){
        int s = i / 130, off = i - s*130;
        seqw16[s][off] = (unsigned short)(sb[s*2048 + n0 + off] * 80);
    }

    int w = tid >> 6, lane = tid & 63;
    int m = lane & 15, q = lane >> 4;

    // wave w's W_a A-frags (f16, pre-converted): 8 x b128 loads
    uint4 wfu[2][4];
    #pragma unroll
    for (int dtL = 0; dtL < 2; dtL++)
        #pragma unroll
        for (int ki = 0; ki < 4; ki++)
            wfu[dtL][ki] = *(const uint4*)((const char*)wah +
                ((2*w+dtL)*16 + m)*256 + ki*64 + q*16);
    float varg[2][4];
    #pragma unroll
    for (int dtL = 0; dtL < 2; dtL++)
        #pragma unroll
        for (int r = 0; r < 4; r++)
            varg[dtL][r] = va[(2*w+dtL)*16 + q*4 + r];
    __syncthreads();

    const char* tb0 = (const char*)tblH + q*16;
    const char* tb1 = tb0 + 2080;
    const char* tb2 = tb1 + 2080;

    for (int sub = 0; sub < 2; sub++){
        int row = sub*64 + w*16 + m;
        unsigned o0[4], o1[4], o2[4];
        #pragma unroll
        for (int s = 0; s < 4; s++){
            o0[s] = seqw16[s][row];
            o1[s] = seqw16[s][row+1];
            o2[s] = seqw16[s][row+2];
        }
        unsigned V[4][4];   // V[s][ki] = f16x2(chA,chB) after taps+relu
        #pragma unroll
        for (int s = 0; s < 4; s++){
            uint4 t0 = *(const uint4*)(tb0 + o0[s]);
            uint4 t1 = *(const uint4*)(tb1 + o1[s]);
            uint4 t2 = *(const uint4*)(tb2 + o2[s]);
            V[s][0] = h3relu(t0.x, t1.x, t2.x);
            V[s][1] = h3relu(t0.y, t1.y, t2.y);
            V[s][2] = h3relu(t0.z, t1.z, t2.z);
            V[s][3] = h3relu(t0.w, t1.w, t2.w);
        }
        uint4 own[4];
        #pragma unroll
        for (int ki = 0; ki < 4; ki++){
            uint4 o;
            o.x = __builtin_amdgcn_perm(V[1][ki], V[0][ki], 0x05040100u);  // A_s0,A_s1
            o.y = __builtin_amdgcn_perm(V[3][ki], V[2][ki], 0x05040100u);  // A_s2,A_s3
            o.z = __builtin_amdgcn_perm(V[1][ki], V[0][ki], 0x07060302u);  // B_s0,B_s1
            o.w = __builtin_amdgcn_perm(V[3][ki], V[2][ki], 0x07060302u);  // B_s2,B_s3
            own[ki] = o;
            bshare[(w*4 + ki)*64 + lane] = o;
        }
        __syncthreads();   // bshare ready

        f32x4 acc[2][4];
        #pragma unroll
        for (int dtL = 0; dtL < 2; dtL++)
            #pragma unroll
            for (int rg = 0; rg < 4; rg++) acc[dtL][rg] = (f32x4){0.f,0.f,0.f,0.f};
        #pragma unroll
        for (int rg = 0; rg < 4; rg++){
            #pragma unroll
            for (int ki = 0; ki < 4; ki++){
                union { uint4 u; f16x8 f; } bu, a0, a1;
                bu.u = (rg == w) ? own[ki] : bshare[(rg*4 + ki)*64 + lane];
                a0.u = wfu[0][ki];
                a1.u = wfu[1][ki];
                acc[0][rg] = __builtin_amdgcn_mfma_f32_16x16x32_f16(a0.f, bu.f, acc[0][rg], 0, 0, 0);
                acc[1][rg] = __builtin_amdgcn_mfma_f32_16x16x32_f16(a1.f, bu.f, acc[1][rg], 0, 0, 0);
            }
        }
        #pragma unroll
        for (int rg = 0; rg < 4; rg++){
            float ep = 0.f;
            #pragma unroll
            for (int dtL = 0; dtL < 2; dtL++){
                ep += varg[dtL][0] * tanh_fast(acc[dtL][rg][0]);
                ep += varg[dtL][1] * tanh_fast(acc[dtL][rg][1]);
                ep += varg[dtL][2] * tanh_fast(acc[dtL][rg][2]);
                ep += varg[dtL][3] * tanh_fast(acc[dtL][rg][3]);
            }
            ep += __shfl_xor(ep, 16);
            ep += __shfl_xor(ep, 32);
            if (lane < 16) epar[w][rg*16 + lane] = ep;
        }
        __syncthreads();   // epar ready + bshare consumed
        if (tid < 64){
            float e4 = epar[0][tid] + epar[1][tid] + epar[2][tid] + epar[3][tid];
            ws_e[b*NPOS + n0 + sub*64 + tid] = e4;
        }
    }
}

// KB1: partial weighted pool per (b, 128-n chunk); y2 regenerated from the
// g-layout table. Letters pre-scaled (l*68, ushort).
// part[(b*16+x)*128 + d] written exactly once. No atomics, no out pre-state.
__global__ __launch_bounds__(256, 8) void kb1_pool(
        const int* __restrict__ seq, const unsigned* __restrict__ tblg,
        const float* __restrict__ ws_e, float* __restrict__ part)
{
    __shared__ unsigned tblG[1332];            // 5328 B (1326 used)
    __shared__ unsigned short seqw16[4][132];  // pre-scaled offsets (x68)
    __shared__ float wlds[128];
    __shared__ float red[4], red2[4];
    __shared__ float red3[4][16][8];

    int tid = threadIdx.x;
    int b = blockIdx.y;
    int x = blockIdx.x;
    int n0 = x * 128;

    for (int i = tid; i < 333; i += 256)
        ((uint4*)tblG)[i] = ((const uint4*)tblg)[i];
    const int* sb = seq + (size_t)b * LSEQ;
    for (int i = tid; i < 4*130; i += 256){
        int s = i / 130, off = i - s*130;
        seqw16[s][off] = (unsigned short)(sb[s*2048 + n0 + off] * 68);
    }

    // softmax stats over the full e row
    const float* e = ws_e + b*NPOS;
    float ev[8];
    #pragma unroll
    for (int r = 0; r < 8; r++) ev[r] = e[tid + r*256];
    int wave = tid >> 6, lane = tid & 63;
    float mx = -1e30f;
    #pragma unroll
    for (int r = 0; r < 8; r++) mx = fmaxf(mx, ev[r]);
    #pragma unroll
    for (int off = 32; off >= 1; off >>= 1) mx = fmaxf(mx, __shfl_xor(mx, off));
    if (lane == 0) red[wave] = mx;
    __syncthreads();
    mx = fmaxf(fmaxf(red[0], red[1]), fmaxf(red[2], red[3]));
    float sum = 0.f;
    #pragma unroll
    for (int r = 0; r < 8; r++) sum += __expf(ev[r] - mx);
    #pragma unroll
    for (int off = 32; off >= 1; off >>= 1) sum += __shfl_xor(sum, off);
    if (lane == 0) red2[wave] = sum;
    __syncthreads();
    float rs = 1.0f / (red2[0] + red2[1] + red2[2] + red2[3]);
    if (tid < 128) wlds[tid] = __expf(e[n0 + tid] - mx) * rs;
    __syncthreads();

    // pool: thread (g = tid&15 -> channel pair, nn = tid>>4) over n = it*16+nn
    int g = tid & 15, nn = tid >> 4;
    const char* g0 = (const char*)tblG + g*4;
    const char* g1 = g0 + 1768;
    const char* g2 = g1 + 1768;
    float acc[8] = {0,0,0,0,0,0,0,0};
    for (int it = 0; it < 8; it++){
        int n = it*16 + nn;
        float wgt = wlds[n];
        unsigned o0[4], o1[4], o2[4];
        #pragma unroll
        for (int s = 0; s < 4; s++){
            o0[s] = seqw16[s][n];
            o1[s] = seqw16[s][n+1];
            o2[s] = seqw16[s][n+2];
        }
        #pragma unroll
        for (int s = 0; s < 4; s++){
            union { f16x2 h; unsigned u; } uv;
            uv.u = h3relu(*(const unsigned*)(g0 + o0[s]),
                          *(const unsigned*)(g1 + o1[s]),
                          *(const unsigned*)(g2 + o2[s]));
            acc[s]   += wgt * (float)uv.h[0];
            acc[4+s] += wgt * (float)uv.h[1];
        }
    }
    #pragma unroll
    for (int j = 0; j < 8; j++){
        acc[j] += __shfl_xor(acc[j], 16);
        acc[j] += __shfl_xor(acc[j], 32);
    }
    if (lane < 16){
        #pragma unroll
        for (int j = 0; j < 8; j++) red3[wave][lane][j] = acc[j];
    }
    __syncthreads();
    if (tid < 128){
        int gg = tid >> 3, jj = tid & 7;
        part[((size_t)b*16 + x)*128 + tid] =
            red3[0][gg][jj] + red3[1][gg][jj] + red3[2][gg][jj] + red3[3][gg][jj];
    }
}

// KB2: out[b][d] = sum_x part[b][x][d] — deterministic direct store
__global__ __launch_bounds__(128) void kb2_finish(const float* __restrict__ part,
        float* __restrict__ out)
{
    int b = blockIdx.x, d = threadIdx.x;
    const float* p = part + (size_t)b*16*128 + d;
    float s = 0.f;
    #pragma unroll
    for (int x = 0; x < 16; x++) s += p[x*128];
    out[b*128 + d] = s;
}

extern "C" void kernel_launch(void* const* d_in, const int* in_sizes, int n_in,
                              void* d_out, int out_size, void* d_ws, size_t ws_size,
                              hipStream_t stream)
{
    const int*   seq = (const int*)d_in[0];
    const float* emb = (const float*)d_in[1];
    const float* cw  = (const float*)d_in[2];
    const float* cb  = (const float*)d_in[3];
    const float* Wa  = (const float*)d_in[4];
    const float* va  = (const float*)d_in[5];
    float* out = (float*)d_out;

    char* wsb = (char*)d_ws;
    float*    ws_e = (float*)wsb;                            // 1 MiB
    float*    part = (float*)(wsb + (1<<20));                // 1 MiB (128*16*128 f32)
    unsigned* tblp = (unsigned*)(wsb + (2<<20));             // 6240 B
    unsigned* tblg = (unsigned*)(wsb + (2<<20) + 8192);      // 5328 B
    unsigned* wah  = (unsigned*)(wsb + (2<<20) + 16384);     // 32 KiB

    k_tbl       <<<5,            256, 0, stream>>>(emb, cw, cb, Wa, tblp, tblg, wah);
    ka_conv_gemm<<<dim3(16,128), 256, 0, stream>>>(seq, tblp, wah, va, ws_e);
    kb1_pool    <<<dim3(16,128), 256, 0, stream>>>(seq, tblg, ws_e, part);
    kb2_finish  <<<128,          128, 0, stream>>>(part, out);
}

// Round 11
// 117.381 us; speedup vs baseline: 1.5575x; 1.5575x over previous
//
#include <hip/hip_runtime.h>

#define LSEQ 8194
#define NPOS 2048

typedef _Float16 f16x8 __attribute__((ext_vector_type(8)));
typedef _Float16 f16x2 __attribute__((ext_vector_type(2)));
typedef __attribute__((ext_vector_type(4))) float f32x4;

static __device__ __forceinline__ float tanh_fast(float x){
    float p = __expf(2.0f * x);
    float r = __builtin_amdgcn_rcpf(1.0f + p);
    return 1.0f - 2.0f * r;
}
// sum 3 packed-f16x2 taps + relu (v_pk_add_f16 + v_pk_max_f16)
static __device__ __forceinline__ unsigned h3relu(unsigned a, unsigned b, unsigned c){
    union { f16x2 h; unsigned u; } x, y, z, r;
    x.u = a; y.u = b; z.u = c;
    f16x2 s = x.h + y.h + z.h;
    f16x2 zero = { (_Float16)0.0f, (_Float16)0.0f };
    r.h = __builtin_elementwise_max(s, zero);
    return r.u;
}
static __device__ __forceinline__ unsigned hpack(float a, float b){
    union { f16x2 h; unsigned u; } pk;
    pk.h = (f16x2){ (_Float16)a, (_Float16)b };
    return pk.u;
}

// K0: precompute shared tables once:
//  tblp: perm-layout tap table [3][26][20] u32 (f16x2), pos p=(cp&3)*4+(cp>>2)
//  tblg: g-layout  tap table [3][26][17] u32 (f16x2)
//  wah : Wa as f16 row-major 128x128 (8192 u32 pairs)
__global__ __launch_bounds__(256) void k_tbl(
        const float* __restrict__ emb, const float* __restrict__ cw,
        const float* __restrict__ cb, const float* __restrict__ Wa,
        unsigned* __restrict__ tblp, unsigned* __restrict__ tblg,
        unsigned* __restrict__ wah)
{
    int gid = blockIdx.x*256 + threadIdx.x;
    if (gid < 1248){
        int k = gid / 416;          // 416 = 26*16
        int rem = gid - k*416;
        int l = rem >> 4;
        int cp = rem & 15;
        int c0 = cp*2;
        float v0 = 0.f, v1 = 0.f;
        #pragma unroll
        for (int i = 0; i < 5; i++){
            float e = emb[l*5 + i];
            v0 += cw[(c0*5 + i)*3 + k] * e;
            v1 += cw[((c0+1)*5 + i)*3 + k] * e;
        }
        if (k == 2){ v0 += cb[c0]; v1 += cb[c0+1]; }
        unsigned u = hpack(v0, v1);
        tblp[k*520 + l*20 + (cp & 3)*4 + (cp >> 2)] = u;
        tblg[k*442 + l*17 + cp] = u;
    }
    for (int i = gid; i < 8192; i += 1280)
        wah[i] = hpack(Wa[2*i], Wa[2*i + 1]);
}

// KA: fused conv + attention-GEMM -> e[b,n]. 128 n per block, 2 sub-tiles.
// Wave w owns d-dims [32w,32w+32). Letters staged as pre-scaled byte offsets
// (l*80, ushort). bounds (256,4): NO forced 6-occupancy (R10 spilled at 40
// VGPRs -> 355 MB scratch traffic). LDS 24.6 KB still allows 6 blocks/CU
// if natural VGPR alloc <= 85. Own-rg B-frags kept in registers.
__global__ __launch_bounds__(256, 4) void ka_conv_gemm(
        const int* __restrict__ seq, const unsigned* __restrict__ tblp,
        const unsigned* __restrict__ wah, const float* __restrict__ va,
        float* __restrict__ ws_e)
{
    __shared__ __align__(16) unsigned tblH[1560];      // 6240 B
    __shared__ unsigned short seqw16[4][132];          // pre-scaled offsets (x80)
    __shared__ uint4 bshare[16*64];                    // 16 KB f16 B-frags
    __shared__ float epar[4][64];

    int tid = threadIdx.x;
    int b   = blockIdx.y;
    int n0  = blockIdx.x * 128;

    for (int i = tid; i < 390; i += 256)
        ((uint4*)tblH)[i] = ((const uint4*)tblp)[i];
    const int* sb = seq + (size_t)b * LSEQ;
    for (int i = tid; i < 4*130; i += 256){
        int s = i / 130, off = i - s*130;
        seqw16[s][off] = (unsigned short)(sb[s*2048 + n0 + off] * 80);
    }

    int w = tid >> 6, lane = tid & 63;
    int m = lane & 15, q = lane >> 4;

    // wave w's W_a A-frags (f16, pre-converted): 8 x b128 loads
    uint4 wfu[2][4];
    #pragma unroll
    for (int dtL = 0; dtL < 2; dtL++)
        #pragma unroll
        for (int ki = 0; ki < 4; ki++)
            wfu[dtL][ki] = *(const uint4*)((const char*)wah +
                ((2*w+dtL)*16 + m)*256 + ki*64 + q*16);
    float varg[2][4];
    #pragma unroll
    for (int dtL = 0; dtL < 2; dtL++)
        #pragma unroll
        for (int r = 0; r < 4; r++)
            varg[dtL][r] = va[(2*w+dtL)*16 + q*4 + r];
    __syncthreads();

    const char* tb0 = (const char*)tblH + q*16;
    const char* tb1 = tb0 + 2080;
    const char* tb2 = tb1 + 2080;

    for (int sub = 0; sub < 2; sub++){
        int row = sub*64 + w*16 + m;
        unsigned o0[4], o1[4], o2[4];
        #pragma unroll
        for (int s = 0; s < 4; s++){
            o0[s] = seqw16[s][row];
            o1[s] = seqw16[s][row+1];
            o2[s] = seqw16[s][row+2];
        }
        unsigned V[4][4];   // V[s][ki] = f16x2(chA,chB) after taps+relu
        #pragma unroll
        for (int s = 0; s < 4; s++){
            uint4 t0 = *(const uint4*)(tb0 + o0[s]);
            uint4 t1 = *(const uint4*)(tb1 + o1[s]);
            uint4 t2 = *(const uint4*)(tb2 + o2[s]);
            V[s][0] = h3relu(t0.x, t1.x, t2.x);
            V[s][1] = h3relu(t0.y, t1.y, t2.y);
            V[s][2] = h3relu(t0.z, t1.z, t2.z);
            V[s][3] = h3relu(t0.w, t1.w, t2.w);
        }
        uint4 own[4];
        #pragma unroll
        for (int ki = 0; ki < 4; ki++){
            uint4 o;
            o.x = __builtin_amdgcn_perm(V[1][ki], V[0][ki], 0x05040100u);  // A_s0,A_s1
            o.y = __builtin_amdgcn_perm(V[3][ki], V[2][ki], 0x05040100u);  // A_s2,A_s3
            o.z = __builtin_amdgcn_perm(V[1][ki], V[0][ki], 0x07060302u);  // B_s0,B_s1
            o.w = __builtin_amdgcn_perm(V[3][ki], V[2][ki], 0x07060302u);  // B_s2,B_s3
            own[ki] = o;
            bshare[(w*4 + ki)*64 + lane] = o;
        }
        __syncthreads();   // bshare ready

        f32x4 acc[2][4];
        #pragma unroll
        for (int dtL = 0; dtL < 2; dtL++)
            #pragma unroll
            for (int rg = 0; rg < 4; rg++) acc[dtL][rg] = (f32x4){0.f,0.f,0.f,0.f};
        #pragma unroll
        for (int rg = 0; rg < 4; rg++){
            #pragma unroll
            for (int ki = 0; ki < 4; ki++){
                union { uint4 u; f16x8 f; } bu, a0, a1;
                bu.u = (rg == w) ? own[ki] : bshare[(rg*4 + ki)*64 + lane];
                a0.u = wfu[0][ki];
                a1.u = wfu[1][ki];
                acc[0][rg] = __builtin_amdgcn_mfma_f32_16x16x32_f16(a0.f, bu.f, acc[0][rg], 0, 0, 0);
                acc[1][rg] = __builtin_amdgcn_mfma_f32_16x16x32_f16(a1.f, bu.f, acc[1][rg], 0, 0, 0);
            }
        }
        #pragma unroll
        for (int rg = 0; rg < 4; rg++){
            float ep = 0.f;
            #pragma unroll
            for (int dtL = 0; dtL < 2; dtL++){
                ep += varg[dtL][0] * tanh_fast(acc[dtL][rg][0]);
                ep += varg[dtL][1] * tanh_fast(acc[dtL][rg][1]);
                ep += varg[dtL][2] * tanh_fast(acc[dtL][rg][2]);
                ep += varg[dtL][3] * tanh_fast(acc[dtL][rg][3]);
            }
            ep += __shfl_xor(ep, 16);
            ep += __shfl_xor(ep, 32);
            if (lane < 16) epar[w][rg*16 + lane] = ep;
        }
        __syncthreads();   // epar ready + bshare consumed
        if (tid < 64){
            float e4 = epar[0][tid] + epar[1][tid] + epar[2][tid] + epar[3][tid];
            ws_e[b*NPOS + n0 + sub*64 + tid] = e4;
        }
    }
}

// KB1: partial weighted pool per (b, 128-n chunk); y2 regenerated from the
// g-layout table. Letters pre-scaled (l*68, ushort).
// part[(b*16+x)*128 + d] written exactly once. No atomics, no out pre-state.
__global__ __launch_bounds__(256, 4) void kb1_pool(
        const int* __restrict__ seq, const unsigned* __restrict__ tblg,
        const float* __restrict__ ws_e, float* __restrict__ part)
{
    __shared__ unsigned tblG[1332];            // 5328 B (1326 used)
    __shared__ unsigned short seqw16[4][132];  // pre-scaled offsets (x68)
    __shared__ float wlds[128];
    __shared__ float red[4], red2[4];
    __shared__ float red3[4][16][8];

    int tid = threadIdx.x;
    int b = blockIdx.y;
    int x = blockIdx.x;
    int n0 = x * 128;

    for (int i = tid; i < 333; i += 256)
        ((uint4*)tblG)[i] = ((const uint4*)tblg)[i];
    const int* sb = seq + (size_t)b * LSEQ;
    for (int i = tid; i < 4*130; i += 256){
        int s = i / 130, off = i - s*130;
        seqw16[s][off] = (unsigned short)(sb[s*2048 + n0 + off] * 68);
    }

    // softmax stats over the full e row
    const float* e = ws_e + b*NPOS;
    float ev[8];
    #pragma unroll
    for (int r = 0; r < 8; r++) ev[r] = e[tid + r*256];
    int wave = tid >> 6, lane = tid & 63;
    float mx = -1e30f;
    #pragma unroll
    for (int r = 0; r < 8; r++) mx = fmaxf(mx, ev[r]);
    #pragma unroll
    for (int off = 32; off >= 1; off >>= 1) mx = fmaxf(mx, __shfl_xor(mx, off));
    if (lane == 0) red[wave] = mx;
    __syncthreads();
    mx = fmaxf(fmaxf(red[0], red[1]), fmaxf(red[2], red[3]));
    float sum = 0.f;
    #pragma unroll
    for (int r = 0; r < 8; r++) sum += __expf(ev[r] - mx);
    #pragma unroll
    for (int off = 32; off >= 1; off >>= 1) sum += __shfl_xor(sum, off);
    if (lane == 0) red2[wave] = sum;
    __syncthreads();
    float rs = 1.0f / (red2[0] + red2[1] + red2[2] + red2[3]);
    if (tid < 128) wlds[tid] = __expf(e[n0 + tid] - mx) * rs;
    __syncthreads();

    // pool: thread (g = tid&15 -> channel pair, nn = tid>>4) over n = it*16+nn
    int g = tid & 15, nn = tid >> 4;
    const char* g0 = (const char*)tblG + g*4;
    const char* g1 = g0 + 1768;
    const char* g2 = g1 + 1768;
    float acc[8] = {0,0,0,0,0,0,0,0};
    for (int it = 0; it < 8; it++){
        int n = it*16 + nn;
        float wgt = wlds[n];
        unsigned o0[4], o1[4], o2[4];
        #pragma unroll
        for (int s = 0; s < 4; s++){
            o0[s] = seqw16[s][n];
            o1[s] = seqw16[s][n+1];
            o2[s] = seqw16[s][n+2];
        }
        #pragma unroll
        for (int s = 0; s < 4; s++){
            union { f16x2 h; unsigned u; } uv;
            uv.u = h3relu(*(const unsigned*)(g0 + o0[s]),
                          *(const unsigned*)(g1 + o1[s]),
                          *(const unsigned*)(g2 + o2[s]));
            acc[s]   += wgt * (float)uv.h[0];
            acc[4+s] += wgt * (float)uv.h[1];
        }
    }
    #pragma unroll
    for (int j = 0; j < 8; j++){
        acc[j] += __shfl_xor(acc[j], 16);
        acc[j] += __shfl_xor(acc[j], 32);
    }
    if (lane < 16){
        #pragma unroll
        for (int j = 0; j < 8; j++) red3[wave][lane][j] = acc[j];
    }
    __syncthreads();
    if (tid < 128){
        int gg = tid >> 3, jj = tid & 7;
        part[((size_t)b*16 + x)*128 + tid] =
            red3[0][gg][jj] + red3[1][gg][jj] + red3[2][gg][jj] + red3[3][gg][jj];
    }
}

// KB2: out[b][d] = sum_x part[b][x][d] — deterministic direct store
__global__ __launch_bounds__(128) void kb2_finish(const float* __restrict__ part,
        float* __restrict__ out)
{
    int b = blockIdx.x, d = threadIdx.x;
    const float* p = part + (size_t)b*16*128 + d;
    float s = 0.f;
    #pragma unroll
    for (int x = 0; x < 16; x++) s += p[x*128];
    out[b*128 + d] = s;
}

extern "C" void kernel_launch(void* const* d_in, const int* in_sizes, int n_in,
                              void* d_out, int out_size, void* d_ws, size_t ws_size,
                              hipStream_t stream)
{
    const int*   seq = (const int*)d_in[0];
    const float* emb = (const float*)d_in[1];
    const float* cw  = (const float*)d_in[2];
    const float* cb  = (const float*)d_in[3];
    const float* Wa  = (const float*)d_in[4];
    const float* va  = (const float*)d_in[5];
    float* out = (float*)d_out;

    char* wsb = (char*)d_ws;
    float*    ws_e = (float*)wsb;                            // 1 MiB
    float*    part = (float*)(wsb + (1<<20));                // 1 MiB (128*16*128 f32)
    unsigned* tblp = (unsigned*)(wsb + (2<<20));             // 6240 B
    unsigned* tblg = (unsigned*)(wsb + (2<<20) + 8192);      // 5328 B
    unsigned* wah  = (unsigned*)(wsb + (2<<20) + 16384);     // 32 KiB

    k_tbl       <<<5,            256, 0, stream>>>(emb, cw, cb, Wa, tblp, tblg, wah);
    ka_conv_gemm<<<dim3(16,128), 256, 0, stream>>>(seq, tblp, wah, va, ws_e);
    kb1_pool    <<<dim3(16,128), 256, 0, stream>>>(seq, tblg, ws_e, part);
    kb2_finish  <<<128,          128, 0, stream>>>(part, out);
}

// Round 12
// 106.051 us; speedup vs baseline: 1.7239x; 1.1068x over previous
//
#include <hip/hip_runtime.h>

#define LSEQ 8194
#define NPOS 2048

typedef _Float16 f16x8 __attribute__((ext_vector_type(8)));
typedef _Float16 f16x2 __attribute__((ext_vector_type(2)));
typedef __attribute__((ext_vector_type(4))) float f32x4;

static __device__ __forceinline__ float tanh_fast(float x){
    float p = __expf(2.0f * x);
    float r = __builtin_amdgcn_rcpf(1.0f + p);
    return 1.0f - 2.0f * r;
}
// sum 3 packed-f16x2 taps + relu (v_pk_add_f16 + v_pk_max_f16)
static __device__ __forceinline__ unsigned h3relu(unsigned a, unsigned b, unsigned c){
    union { f16x2 h; unsigned u; } x, y, z, r;
    x.u = a; y.u = b; z.u = c;
    f16x2 s = x.h + y.h + z.h;
    f16x2 zero = { (_Float16)0.0f, (_Float16)0.0f };
    r.h = __builtin_elementwise_max(s, zero);
    return r.u;
}
static __device__ __forceinline__ unsigned hpack(float a, float b){
    union { f16x2 h; unsigned u; } pk;
    pk.h = (f16x2){ (_Float16)a, (_Float16)b };
    return pk.u;
}

// K0: precompute shared tables once:
//  tblp: perm-layout tap table [3][26][20] u32 (f16x2), pos p=(cp&3)*4+(cp>>2)
//        -> b128 at [letter][q*4] = ch-pairs for cp=ki*4+q, ki=0..3
//  wah : Wa as f16 row-major 128x128 (8192 u32 pairs)
__global__ __launch_bounds__(256) void k_tbl(
        const float* __restrict__ emb, const float* __restrict__ cw,
        const float* __restrict__ cb, const float* __restrict__ Wa,
        unsigned* __restrict__ tblp, unsigned* __restrict__ wah)
{
    int gid = blockIdx.x*256 + threadIdx.x;
    if (gid < 1248){
        int k = gid / 416;          // 416 = 26*16
        int rem = gid - k*416;
        int l = rem >> 4;
        int cp = rem & 15;
        int c0 = cp*2;
        float v0 = 0.f, v1 = 0.f;
        #pragma unroll
        for (int i = 0; i < 5; i++){
            float e = emb[l*5 + i];
            v0 += cw[(c0*5 + i)*3 + k] * e;
            v1 += cw[((c0+1)*5 + i)*3 + k] * e;
        }
        if (k == 2){ v0 += cb[c0]; v1 += cb[c0+1]; }
        tblp[k*520 + l*20 + (cp & 3)*4 + (cp >> 2)] = hpack(v0, v1);
    }
    for (int i = gid; i < 8192; i += 1280)
        wah[i] = hpack(Wa[2*i], Wa[2*i + 1]);
}

// KA: fused conv + attention-GEMM -> e[b,n]. 128 n per block, 2 sub-tiles.
// Wave w owns d-dims [32w,32w+32). Letters staged as pre-scaled byte offsets
// (l*80, ushort). R9-exact (own-rg trick reverted: its 64 cndmask/sub cost
// more than the 4 ds_read_b128 it saved).
__global__ __launch_bounds__(256, 4) void ka_conv_gemm(
        const int* __restrict__ seq, const unsigned* __restrict__ tblp,
        const unsigned* __restrict__ wah, const float* __restrict__ va,
        float* __restrict__ ws_e)
{
    __shared__ __align__(16) unsigned tblH[1560];      // 6240 B
    __shared__ unsigned short seqw16[4][132];          // pre-scaled offsets (x80)
    __shared__ uint4 bshare[16*64];                    // 16 KB f16 B-frags
    __shared__ float epar[4][64];

    int tid = threadIdx.x;
    int b   = blockIdx.y;
    int n0  = blockIdx.x * 128;

    for (int i = tid; i < 390; i += 256)
        ((uint4*)tblH)[i] = ((const uint4*)tblp)[i];
    const int* sb = seq + (size_t)b * LSEQ;
    for (int i = tid; i < 4*130; i += 256){
        int s = i / 130, off = i - s*130;
        seqw16[s][off] = (unsigned short)(sb[s*2048 + n0 + off] * 80);
    }

    int w = tid >> 6, lane = tid & 63;
    int m = lane & 15, q = lane >> 4;

    // wave w's W_a A-frags (f16, pre-converted): 8 x b128 loads
    uint4 wfu[2][4];
    #pragma unroll
    for (int dtL = 0; dtL < 2; dtL++)
        #pragma unroll
        for (int ki = 0; ki < 4; ki++)
            wfu[dtL][ki] = *(const uint4*)((const char*)wah +
                ((2*w+dtL)*16 + m)*256 + ki*64 + q*16);
    float varg[2][4];
    #pragma unroll
    for (int dtL = 0; dtL < 2; dtL++)
        #pragma unroll
        for (int r = 0; r < 4; r++)
            varg[dtL][r] = va[(2*w+dtL)*16 + q*4 + r];
    __syncthreads();

    const char* tb0 = (const char*)tblH + q*16;
    const char* tb1 = tb0 + 2080;
    const char* tb2 = tb1 + 2080;

    for (int sub = 0; sub < 2; sub++){
        int row = sub*64 + w*16 + m;
        unsigned o0[4], o1[4], o2[4];
        #pragma unroll
        for (int s = 0; s < 4; s++){
            o0[s] = seqw16[s][row];
            o1[s] = seqw16[s][row+1];
            o2[s] = seqw16[s][row+2];
        }
        unsigned V[4][4];   // V[s][ki] = f16x2(chA,chB) after taps+relu
        #pragma unroll
        for (int s = 0; s < 4; s++){
            uint4 t0 = *(const uint4*)(tb0 + o0[s]);
            uint4 t1 = *(const uint4*)(tb1 + o1[s]);
            uint4 t2 = *(const uint4*)(tb2 + o2[s]);
            V[s][0] = h3relu(t0.x, t1.x, t2.x);
            V[s][1] = h3relu(t0.y, t1.y, t2.y);
            V[s][2] = h3relu(t0.z, t1.z, t2.z);
            V[s][3] = h3relu(t0.w, t1.w, t2.w);
        }
        #pragma unroll
        for (int ki = 0; ki < 4; ki++){
            uint4 o;
            o.x = __builtin_amdgcn_perm(V[1][ki], V[0][ki], 0x05040100u);  // A_s0,A_s1
            o.y = __builtin_amdgcn_perm(V[3][ki], V[2][ki], 0x05040100u);  // A_s2,A_s3
            o.z = __builtin_amdgcn_perm(V[1][ki], V[0][ki], 0x07060302u);  // B_s0,B_s1
            o.w = __builtin_amdgcn_perm(V[3][ki], V[2][ki], 0x07060302u);  // B_s2,B_s3
            bshare[(w*4 + ki)*64 + lane] = o;
        }
        __syncthreads();   // bshare ready

        f32x4 acc[2][4];
        #pragma unroll
        for (int dtL = 0; dtL < 2; dtL++)
            #pragma unroll
            for (int rg = 0; rg < 4; rg++) acc[dtL][rg] = (f32x4){0.f,0.f,0.f,0.f};
        #pragma unroll
        for (int rg = 0; rg < 4; rg++){
            #pragma unroll
            for (int ki = 0; ki < 4; ki++){
                union { uint4 u; f16x8 f; } bu, a0, a1;
                bu.u = bshare[(rg*4 + ki)*64 + lane];
                a0.u = wfu[0][ki];
                a1.u = wfu[1][ki];
                acc[0][rg] = __builtin_amdgcn_mfma_f32_16x16x32_f16(a0.f, bu.f, acc[0][rg], 0, 0, 0);
                acc[1][rg] = __builtin_amdgcn_mfma_f32_16x16x32_f16(a1.f, bu.f, acc[1][rg], 0, 0, 0);
            }
        }
        #pragma unroll
        for (int rg = 0; rg < 4; rg++){
            float ep = 0.f;
            #pragma unroll
            for (int dtL = 0; dtL < 2; dtL++){
                ep += varg[dtL][0] * tanh_fast(acc[dtL][rg][0]);
                ep += varg[dtL][1] * tanh_fast(acc[dtL][rg][1]);
                ep += varg[dtL][2] * tanh_fast(acc[dtL][rg][2]);
                ep += varg[dtL][3] * tanh_fast(acc[dtL][rg][3]);
            }
            ep += __shfl_xor(ep, 16);
            ep += __shfl_xor(ep, 32);
            if (lane < 16) epar[w][rg*16 + lane] = ep;
        }
        __syncthreads();   // epar ready + bshare consumed
        if (tid < 64){
            float e4 = epar[0][tid] + epar[1][tid] + epar[2][tid] + epar[3][tid];
            ws_e[b*NPOS + n0 + sub*64 + tid] = e4;
        }
    }
}

// KB1: partial weighted pool per (b, 256-n chunk) using b128 gathers from the
// SAME perm table as KA: thread (qq=tid&3, nn=tid>>2) serves n with 12
// ds_read_b128 covering 32 d-dims (d = 32ki+8qq+4par+s), 32 f32 acc/thread.
// part[(b*8+x)*128 + d] written exactly once. No atomics, no out pre-state.
__global__ __launch_bounds__(256, 4) void kb1_pool(
        const int* __restrict__ seq, const unsigned* __restrict__ tblp,
        const float* __restrict__ ws_e, float* __restrict__ part)
{
    __shared__ __align__(16) unsigned tblH[1560];      // perm table, 6240 B
    __shared__ unsigned short seqw16[4][260];          // pre-scaled offsets (x80)
    __shared__ float wlds[256];
    __shared__ float red[4], red2[4];
    __shared__ float red3[4][4][32];                   // [wave][qq][a]

    int tid = threadIdx.x;
    int b = blockIdx.y;
    int x = blockIdx.x;
    int n0 = x * 256;

    for (int i = tid; i < 390; i += 256)
        ((uint4*)tblH)[i] = ((const uint4*)tblp)[i];
    const int* sb = seq + (size_t)b * LSEQ;
    for (int i = tid; i < 4*258; i += 256){
        int s = i / 258, off = i - s*258;
        seqw16[s][off] = (unsigned short)(sb[s*2048 + n0 + off] * 80);
    }

    // softmax stats over the full e row
    const float* e = ws_e + b*NPOS;
    float ev[8];
    #pragma unroll
    for (int r = 0; r < 8; r++) ev[r] = e[tid + r*256];
    int wave = tid >> 6, lane = tid & 63;
    float mx = -1e30f;
    #pragma unroll
    for (int r = 0; r < 8; r++) mx = fmaxf(mx, ev[r]);
    #pragma unroll
    for (int off = 32; off >= 1; off >>= 1) mx = fmaxf(mx, __shfl_xor(mx, off));
    if (lane == 0) red[wave] = mx;
    __syncthreads();
    mx = fmaxf(fmaxf(red[0], red[1]), fmaxf(red[2], red[3]));
    float sum = 0.f;
    #pragma unroll
    for (int r = 0; r < 8; r++) sum += __expf(ev[r] - mx);
    #pragma unroll
    for (int off = 32; off >= 1; off >>= 1) sum += __shfl_xor(sum, off);
    if (lane == 0) red2[wave] = sum;
    __syncthreads();
    float rs = 1.0f / (red2[0] + red2[1] + red2[2] + red2[3]);
    wlds[tid] = __expf(e[n0 + tid] - mx) * rs;
    __syncthreads();

    // pool: thread (qq = tid&3, nn = tid>>2) over n = it*64 + nn
    int qq = tid & 3, nn = tid >> 2;
    const char* t0 = (const char*)tblH + qq*16;
    const char* t1 = t0 + 2080;
    const char* t2 = t1 + 2080;
    float acc[32];
    #pragma unroll
    for (int j = 0; j < 32; j++) acc[j] = 0.f;
    for (int it = 0; it < 4; it++){
        int n = it*64 + nn;
        float wgt = wlds[n];
        unsigned o0[4], o1[4], o2[4];
        #pragma unroll
        for (int s = 0; s < 4; s++){
            o0[s] = seqw16[s][n];
            o1[s] = seqw16[s][n+1];
            o2[s] = seqw16[s][n+2];
        }
        #pragma unroll
        for (int s = 0; s < 4; s++){
            uint4 a = *(const uint4*)(t0 + o0[s]);
            uint4 bb = *(const uint4*)(t1 + o1[s]);
            uint4 c = *(const uint4*)(t2 + o2[s]);
            union { f16x2 h; unsigned u; } u0, u1, u2, u3;
            u0.u = h3relu(a.x, bb.x, c.x);   // ki=0: ch pair (8*0+2qq, +1)
            u1.u = h3relu(a.y, bb.y, c.y);   // ki=1
            u2.u = h3relu(a.z, bb.z, c.z);   // ki=2
            u3.u = h3relu(a.w, bb.w, c.w);   // ki=3
            acc[0*8 + 0*4 + s] += wgt * (float)u0.h[0];
            acc[0*8 + 1*4 + s] += wgt * (float)u0.h[1];
            acc[1*8 + 0*4 + s] += wgt * (float)u1.h[0];
            acc[1*8 + 1*4 + s] += wgt * (float)u1.h[1];
            acc[2*8 + 0*4 + s] += wgt * (float)u2.h[0];
            acc[2*8 + 1*4 + s] += wgt * (float)u2.h[1];
            acc[3*8 + 0*4 + s] += wgt * (float)u3.h[0];
            acc[3*8 + 1*4 + s] += wgt * (float)u3.h[1];
        }
    }
    // reduce over nn within wave (xor bits 2..5); lanes 0..3 end with qq=0..3 sums
    #pragma unroll
    for (int j = 0; j < 32; j++){
        acc[j] += __shfl_xor(acc[j], 4);
        acc[j] += __shfl_xor(acc[j], 8);
        acc[j] += __shfl_xor(acc[j], 16);
        acc[j] += __shfl_xor(acc[j], 32);
    }
    if (lane < 4){
        #pragma unroll
        for (int j = 0; j < 32; j++) red3[wave][lane][j] = acc[j];
    }
    __syncthreads();
    if (tid < 128){
        // d = tid: ki=d>>5, qq=(d>>3)&3, par=(d>>2)&1, s=d&3; a=ki*8+par*4+s
        int ki = tid >> 5, q2 = (tid >> 3) & 3, par = (tid >> 2) & 1, s = tid & 3;
        int a = ki*8 + par*4 + s;
        part[((size_t)b*8 + x)*128 + tid] =
            red3[0][q2][a] + red3[1][q2][a] + red3[2][q2][a] + red3[3][q2][a];
    }
}

// KB2: out[b][d] = sum_x part[b][x][d] — deterministic direct store
__global__ __launch_bounds__(128) void kb2_finish(const float* __restrict__ part,
        float* __restrict__ out)
{
    int b = blockIdx.x, d = threadIdx.x;
    const float* p = part + (size_t)b*8*128 + d;
    float s = 0.f;
    #pragma unroll
    for (int x = 0; x < 8; x++) s += p[x*128];
    out[b*128 + d] = s;
}

extern "C" void kernel_launch(void* const* d_in, const int* in_sizes, int n_in,
                              void* d_out, int out_size, void* d_ws, size_t ws_size,
                              hipStream_t stream)
{
    const int*   seq = (const int*)d_in[0];
    const float* emb = (const float*)d_in[1];
    const float* cw  = (const float*)d_in[2];
    const float* cb  = (const float*)d_in[3];
    const float* Wa  = (const float*)d_in[4];
    const float* va  = (const float*)d_in[5];
    float* out = (float*)d_out;

    char* wsb = (char*)d_ws;
    float*    ws_e = (float*)wsb;                            // 1 MiB
    float*    part = (float*)(wsb + (1<<20));                // 512 KiB (128*8*128 f32)
    unsigned* tblp = (unsigned*)(wsb + (2<<20));             // 6240 B
    unsigned* wah  = (unsigned*)(wsb + (2<<20) + 16384);     // 32 KiB

    k_tbl       <<<5,            256, 0, stream>>>(emb, cw, cb, Wa, tblp, wah);
    ka_conv_gemm<<<dim3(16,128), 256, 0, stream>>>(seq, tblp, wah, va, ws_e);
    kb1_pool    <<<dim3(8,128),  256, 0, stream>>>(seq, tblp, ws_e, part);
    kb2_finish  <<<128,          128, 0, stream>>>(part, out);
}

// Round 14
// 98.336 us; speedup vs baseline: 1.8592x; 1.0785x over previous
//
#include <hip/hip_runtime.h>

#define LSEQ 8194
#define NPOS 2048

typedef _Float16 f16x8 __attribute__((ext_vector_type(8)));
typedef _Float16 f16x2 __attribute__((ext_vector_type(2)));
typedef __attribute__((ext_vector_type(4))) float f32x4;

static __device__ __forceinline__ float tanh_fast(float x){
    float p = __expf(2.0f * x);
    float r = __builtin_amdgcn_rcpf(1.0f + p);
    return 1.0f - 2.0f * r;
}
// sum 3 packed-f16x2 taps + relu (v_pk_add_f16 + v_pk_max_f16)
static __device__ __forceinline__ unsigned h3relu(unsigned a, unsigned b, unsigned c){
    union { f16x2 h; unsigned u; } x, y, z, r;
    x.u = a; y.u = b; z.u = c;
    f16x2 s = x.h + y.h + z.h;
    f16x2 zero = { (_Float16)0.0f, (_Float16)0.0f };
    r.h = __builtin_elementwise_max(s, zero);
    return r.u;
}
static __device__ __forceinline__ unsigned hpack(float a, float b){
    union { f16x2 h; unsigned u; } pk;
    pk.h = (f16x2){ (_Float16)a, (_Float16)b };
    return pk.u;
}

// K0: precompute shared tables once:
//  tblp: perm-layout tap table [3][26][20] u32 (f16x2), pos p=(cp&3)*4+(cp>>2)
//  wah : Wa as f16 row-major 128x128 (8192 u32 pairs)
__global__ __launch_bounds__(256) void k_tbl(
        const float* __restrict__ emb, const float* __restrict__ cw,
        const float* __restrict__ cb, const float* __restrict__ Wa,
        unsigned* __restrict__ tblp, unsigned* __restrict__ wah)
{
    int gid = blockIdx.x*256 + threadIdx.x;
    if (gid < 1248){
        int k = gid / 416;          // 416 = 26*16
        int rem = gid - k*416;
        int l = rem >> 4;
        int cp = rem & 15;
        int c0 = cp*2;
        float v0 = 0.f, v1 = 0.f;
        #pragma unroll
        for (int i = 0; i < 5; i++){
            float e = emb[l*5 + i];
            v0 += cw[(c0*5 + i)*3 + k] * e;
            v1 += cw[((c0+1)*5 + i)*3 + k] * e;
        }
        if (k == 2){ v0 += cb[c0]; v1 += cb[c0+1]; }
        tblp[k*520 + l*20 + (cp & 3)*4 + (cp >> 2)] = hpack(v0, v1);
    }
    for (int i = gid; i < 8192; i += 1280)
        wah[i] = hpack(Wa[2*i], Wa[2*i + 1]);
}

// K_FUSED (ordinary launch, grid (8,128)): per (b, 256-n chunk):
// Phase A: conv+GEMM -> e (kept in LDS; no global round-trip).
// Phase B: ONLINE-SOFTMAX local pool: m_x = max e, s_x = sum exp(e-m_x),
//          ctx_part = sum exp(e-m_x)*y (y regenerated via b128 gathers).
// Writes part[(b*8+x)*128+d], stats[(b*8+x)*2] exactly once. No atomics,
// no grid sync, no out pre-state. kb2 combines chunks with exp rescale.
__global__ __launch_bounds__(256, 4) void k_fused(
        const int* __restrict__ seq, const unsigned* __restrict__ tblp,
        const unsigned* __restrict__ wah, const float* __restrict__ va,
        float* __restrict__ part, float* __restrict__ stats)
{
    __shared__ __align__(16) unsigned tblH[1560];      // 6240 B perm table
    __shared__ unsigned short seqw16[4][260];          // pre-scaled offsets (x80)
    __shared__ uint4 bshare[16*64];                    // 16 KB f16 B-frags
    __shared__ float epar[4][64];
    __shared__ float elds[256];                        // e values for this chunk
    __shared__ float wlds[256];                        // exp(e - m_x)
    __shared__ float red[4], red2[4];
    __shared__ float red3[4][4][32];                   // [wave][qq][a]

    int tid = threadIdx.x;
    int b   = blockIdx.y;
    int x   = blockIdx.x;
    int n0  = x * 256;

    for (int i = tid; i < 390; i += 256)
        ((uint4*)tblH)[i] = ((const uint4*)tblp)[i];
    const int* sb = seq + (size_t)b * LSEQ;
    for (int i = tid; i < 4*258; i += 256){
        int s = i / 258, off = i - s*258;
        seqw16[s][off] = (unsigned short)(sb[s*2048 + n0 + off] * 80);
    }

    int w = tid >> 6, lane = tid & 63;
    int m = lane & 15, q = lane >> 4;

    // wave w's W_a A-frags (f16, pre-converted): 8 x b128 loads
    uint4 wfu[2][4];
    #pragma unroll
    for (int dtL = 0; dtL < 2; dtL++)
        #pragma unroll
        for (int ki = 0; ki < 4; ki++)
            wfu[dtL][ki] = *(const uint4*)((const char*)wah +
                ((2*w+dtL)*16 + m)*256 + ki*64 + q*16);
    float varg[2][4];
    #pragma unroll
    for (int dtL = 0; dtL < 2; dtL++)
        #pragma unroll
        for (int r = 0; r < 4; r++)
            varg[dtL][r] = va[(2*w+dtL)*16 + q*4 + r];
    __syncthreads();

    const char* tb0 = (const char*)tblH + q*16;
    const char* tb1 = tb0 + 2080;
    const char* tb2 = tb1 + 2080;

    // ---------------- Phase A: conv + GEMM -> e (into elds) ----------------
    for (int sub = 0; sub < 4; sub++){
        int row = sub*64 + w*16 + m;
        unsigned o0[4], o1[4], o2[4];
        #pragma unroll
        for (int s = 0; s < 4; s++){
            o0[s] = seqw16[s][row];
            o1[s] = seqw16[s][row+1];
            o2[s] = seqw16[s][row+2];
        }
        unsigned V[4][4];   // V[s][ki] = f16x2(chA,chB) after taps+relu
        #pragma unroll
        for (int s = 0; s < 4; s++){
            uint4 t0 = *(const uint4*)(tb0 + o0[s]);
            uint4 t1 = *(const uint4*)(tb1 + o1[s]);
            uint4 t2 = *(const uint4*)(tb2 + o2[s]);
            V[s][0] = h3relu(t0.x, t1.x, t2.x);
            V[s][1] = h3relu(t0.y, t1.y, t2.y);
            V[s][2] = h3relu(t0.z, t1.z, t2.z);
            V[s][3] = h3relu(t0.w, t1.w, t2.w);
        }
        #pragma unroll
        for (int ki = 0; ki < 4; ki++){
            uint4 o;
            o.x = __builtin_amdgcn_perm(V[1][ki], V[0][ki], 0x05040100u);  // A_s0,A_s1
            o.y = __builtin_amdgcn_perm(V[3][ki], V[2][ki], 0x05040100u);  // A_s2,A_s3
            o.z = __builtin_amdgcn_perm(V[1][ki], V[0][ki], 0x07060302u);  // B_s0,B_s1
            o.w = __builtin_amdgcn_perm(V[3][ki], V[2][ki], 0x07060302u);  // B_s2,B_s3
            bshare[(w*4 + ki)*64 + lane] = o;
        }
        __syncthreads();   // bshare ready

        f32x4 acc[2][4];
        #pragma unroll
        for (int dtL = 0; dtL < 2; dtL++)
            #pragma unroll
            for (int rg = 0; rg < 4; rg++) acc[dtL][rg] = (f32x4){0.f,0.f,0.f,0.f};
        #pragma unroll
        for (int rg = 0; rg < 4; rg++){
            #pragma unroll
            for (int ki = 0; ki < 4; ki++){
                union { uint4 u; f16x8 f; } bu, a0, a1;
                bu.u = bshare[(rg*4 + ki)*64 + lane];
                a0.u = wfu[0][ki];
                a1.u = wfu[1][ki];
                acc[0][rg] = __builtin_amdgcn_mfma_f32_16x16x32_f16(a0.f, bu.f, acc[0][rg], 0, 0, 0);
                acc[1][rg] = __builtin_amdgcn_mfma_f32_16x16x32_f16(a1.f, bu.f, acc[1][rg], 0, 0, 0);
            }
        }
        #pragma unroll
        for (int rg = 0; rg < 4; rg++){
            float ep = 0.f;
            #pragma unroll
            for (int dtL = 0; dtL < 2; dtL++){
                ep += varg[dtL][0] * tanh_fast(acc[dtL][rg][0]);
                ep += varg[dtL][1] * tanh_fast(acc[dtL][rg][1]);
                ep += varg[dtL][2] * tanh_fast(acc[dtL][rg][2]);
                ep += varg[dtL][3] * tanh_fast(acc[dtL][rg][3]);
            }
            ep += __shfl_xor(ep, 16);
            ep += __shfl_xor(ep, 32);
            if (lane < 16) epar[w][rg*16 + lane] = ep;
        }
        __syncthreads();   // epar ready + bshare consumed
        if (tid < 64)
            elds[sub*64 + tid] = epar[0][tid] + epar[1][tid] + epar[2][tid] + epar[3][tid];
    }
    __syncthreads();   // elds complete

    // ---------------- Phase B: local (online) softmax + pool ----------------
    float ev = elds[tid];
    float mx = ev;
    #pragma unroll
    for (int off = 32; off >= 1; off >>= 1) mx = fmaxf(mx, __shfl_xor(mx, off));
    if (lane == 0) red[w] = mx;
    __syncthreads();
    mx = fmaxf(fmaxf(red[0], red[1]), fmaxf(red[2], red[3]));   // local chunk max m_x
    float wgt_own = __expf(ev - mx);
    float sum = wgt_own;
    #pragma unroll
    for (int off = 32; off >= 1; off >>= 1) sum += __shfl_xor(sum, off);
    if (lane == 0) red2[w] = sum;
    wlds[tid] = wgt_own;
    __syncthreads();
    float s_x = red2[0] + red2[1] + red2[2] + red2[3];          // local sum

    // pool: thread (qq = tid&3, nn = tid>>2) over n = it*64 + nn;
    // 12 ds_read_b128 per n covering 32 d-dims (d = 32ki+8qq+4par+s)
    int qq = tid & 3, nn = tid >> 2;
    const char* t0 = (const char*)tblH + qq*16;
    const char* t1 = t0 + 2080;
    const char* t2 = t1 + 2080;
    float acc[32];
    #pragma unroll
    for (int j = 0; j < 32; j++) acc[j] = 0.f;
    for (int it = 0; it < 4; it++){
        int n = it*64 + nn;
        float wgt = wlds[n];
        unsigned o0[4], o1[4], o2[4];
        #pragma unroll
        for (int s = 0; s < 4; s++){
            o0[s] = seqw16[s][n];
            o1[s] = seqw16[s][n+1];
            o2[s] = seqw16[s][n+2];
        }
        #pragma unroll
        for (int s = 0; s < 4; s++){
            uint4 a = *(const uint4*)(t0 + o0[s]);
            uint4 bb = *(const uint4*)(t1 + o1[s]);
            uint4 c = *(const uint4*)(t2 + o2[s]);
            union { f16x2 h; unsigned u; } u0, u1, u2, u3;
            u0.u = h3relu(a.x, bb.x, c.x);   // ki=0
            u1.u = h3relu(a.y, bb.y, c.y);   // ki=1
            u2.u = h3relu(a.z, bb.z, c.z);   // ki=2
            u3.u = h3relu(a.w, bb.w, c.w);   // ki=3
            acc[0*8 + 0*4 + s] += wgt * (float)u0.h[0];
            acc[0*8 + 1*4 + s] += wgt * (float)u0.h[1];
            acc[1*8 + 0*4 + s] += wgt * (float)u1.h[0];
            acc[1*8 + 1*4 + s] += wgt * (float)u1.h[1];
            acc[2*8 + 0*4 + s] += wgt * (float)u2.h[0];
            acc[2*8 + 1*4 + s] += wgt * (float)u2.h[1];
            acc[3*8 + 0*4 + s] += wgt * (float)u3.h[0];
            acc[3*8 + 1*4 + s] += wgt * (float)u3.h[1];
        }
    }
    // reduce over nn within wave (xor bits 2..5)
    #pragma unroll
    for (int j = 0; j < 32; j++){
        acc[j] += __shfl_xor(acc[j], 4);
        acc[j] += __shfl_xor(acc[j], 8);
        acc[j] += __shfl_xor(acc[j], 16);
        acc[j] += __shfl_xor(acc[j], 32);
    }
    if (lane < 4){
        #pragma unroll
        for (int j = 0; j < 32; j++) red3[w][lane][j] = acc[j];
    }
    __syncthreads();
    if (tid < 128){
        // d = tid: ki=d>>5, qq=(d>>3)&3, par=(d>>2)&1, s=d&3; a=ki*8+par*4+s
        int ki = tid >> 5, q2 = (tid >> 3) & 3, par = (tid >> 2) & 1, s = tid & 3;
        int a = ki*8 + par*4 + s;
        part[((size_t)b*8 + x)*128 + tid] =
            red3[0][q2][a] + red3[1][q2][a] + red3[2][q2][a] + red3[3][q2][a];
    }
    if (tid == 0){
        stats[((size_t)b*8 + x)*2    ] = mx;
        stats[((size_t)b*8 + x)*2 + 1] = s_x;
    }
}

// KB2: combine chunk partials with online-softmax rescale.
// out[b][d] = sum_x part[b][x][d]*exp(m_x-M) / sum_x s_x*exp(m_x-M)
__global__ __launch_bounds__(128) void kb2_finish(const float* __restrict__ part,
        const float* __restrict__ stats, float* __restrict__ out)
{
    int b = blockIdx.x, d = threadIdx.x;
    const float* st = stats + (size_t)b*16;
    float M = -1e30f;
    #pragma unroll
    for (int x = 0; x < 8; x++) M = fmaxf(M, st[x*2]);
    float f[8], S = 0.f;
    #pragma unroll
    for (int x = 0; x < 8; x++){
        f[x] = __expf(st[x*2] - M);
        S += st[x*2+1] * f[x];
    }
    float inv = 1.0f / S;
    const float* p = part + (size_t)b*8*128 + d;
    float s = 0.f;
    #pragma unroll
    for (int x = 0; x < 8; x++) s += p[x*128] * f[x];
    out[b*128 + d] = s * inv;
}

extern "C" void kernel_launch(void* const* d_in, const int* in_sizes, int n_in,
                              void* d_out, int out_size, void* d_ws, size_t ws_size,
                              hipStream_t stream)
{
    const int*   seq = (const int*)d_in[0];
    const float* emb = (const float*)d_in[1];
    const float* cw  = (const float*)d_in[2];
    const float* cb  = (const float*)d_in[3];
    const float* Wa  = (const float*)d_in[4];
    const float* va  = (const float*)d_in[5];
    float* out = (float*)d_out;

    char* wsb = (char*)d_ws;
    float*    part  = (float*)wsb;                           // 512 KiB (128*8*128 f32)
    float*    stats = (float*)(wsb + (1<<20));               // 8 KiB (128*8*2 f32)
    unsigned* tblp  = (unsigned*)(wsb + (2<<20));            // 6240 B
    unsigned* wah   = (unsigned*)(wsb + (2<<20) + 16384);    // 32 KiB

    k_tbl     <<<5,           256, 0, stream>>>(emb, cw, cb, Wa, tblp, wah);
    k_fused   <<<dim3(8,128), 256, 0, stream>>>(seq, tblp, wah, va, part, stats);
    kb2_finish<<<128,         128, 0, stream>>>(part, stats, out);
}